// Round 1
// baseline (550.420 us; speedup 1.0000x reference)
//
#include <hip/hip_runtime.h>

// 2-layer GCN, pull-based (CSR) aggregation, fp32 throughout.
// Pipeline: count_deg -> scan(rowstart,dinv) -> fill_adj -> gemm1 ->
//           agg1(+bias,relu,residual) -> gemm2 -> agg2(+bias) -> d_out

#define FDIM 128

__global__ void count_deg_kernel(const int* __restrict__ ei, int E, int* __restrict__ deg) {
    int e = blockIdx.x * blockDim.x + threadIdx.x;
    if (e < E) atomicAdd(&deg[ei[E + e]], 1);
}

// Single-block exclusive scan over deg -> rowstart[0..n], plus dinv = rsqrt(deg+1).
__global__ void scan_kernel(const int* __restrict__ deg, int* __restrict__ rowstart,
                            float* __restrict__ dinv, int n) {
    __shared__ int s[1024];
    __shared__ int carry_s;
    if (threadIdx.x == 0) carry_s = 0;
    __syncthreads();
    int nchunks = (n + 1023) / 1024;
    for (int c = 0; c < nchunks; ++c) {
        int i = c * 1024 + threadIdx.x;
        int v = (i < n) ? deg[i] : 0;
        s[threadIdx.x] = v;
        __syncthreads();
        for (int off = 1; off < 1024; off <<= 1) {
            int t = (threadIdx.x >= off) ? s[threadIdx.x - off] : 0;
            __syncthreads();
            s[threadIdx.x] += t;
            __syncthreads();
        }
        if (i < n) {
            rowstart[i] = carry_s + s[threadIdx.x] - v;   // exclusive
            dinv[i] = rsqrtf((float)(v + 1));             // +1 self-loop
        }
        __syncthreads();
        if (threadIdx.x == 0) carry_s += s[1023];
        __syncthreads();
    }
    if (threadIdx.x == 0) rowstart[n] = carry_s;
}

__global__ void fill_adj_kernel(const int* __restrict__ ei, int E,
                                const int* __restrict__ rowstart,
                                int* __restrict__ cursor, int* __restrict__ adj) {
    int e = blockIdx.x * blockDim.x + threadIdx.x;
    if (e >= E) return;
    int src = ei[e];
    int dst = ei[E + e];
    int pos = atomicAdd(&cursor[dst], 1);
    adj[rowstart[dst] + pos] = src;
}

// h1[i,:] = x[i,:] @ W1 ; one row per 128-thread block; W1 is 64KB -> L1/L2 hot.
__global__ void gemm1_kernel(const float* __restrict__ x, const float* __restrict__ W,
                             float* __restrict__ h) {
    __shared__ float xr[FDIM];
    int i = blockIdx.x;
    int j = threadIdx.x;
    xr[j] = x[(size_t)i * FDIM + j];
    __syncthreads();
    float acc = 0.f;
#pragma unroll 8
    for (int k = 0; k < FDIM; ++k) acc += xr[k] * W[k * FDIM + j];
    h[(size_t)i * FDIM + j] = acc;
}

// z[i,:] = relu( dinv[i]*(sum_s h1[s,:]*dinv[s]) + h1[i,:]*dinv[i]^2 + b1 ) + x[i,:]
__global__ void agg1_kernel(const float* __restrict__ h1, const int* __restrict__ rowstart,
                            const int* __restrict__ adj, const float* __restrict__ dinv,
                            const float* __restrict__ x, const float* __restrict__ b1,
                            float* __restrict__ z, int N) {
    int wave = threadIdx.x >> 6;
    int lane = threadIdx.x & 63;
    int i = blockIdx.x * 4 + wave;
    if (i >= N) return;
    int s0 = rowstart[i], s1 = rowstart[i + 1];
    float acc0 = 0.f, acc1 = 0.f;
    for (int n = s0; n < s1; ++n) {
        int s = adj[n];
        float w = dinv[s];
        const float* row = h1 + (size_t)s * FDIM;
        acc0 += row[lane] * w;
        acc1 += row[lane + 64] * w;
    }
    float di = dinv[i];
    float self = di * di;
    const float* rowi = h1 + (size_t)i * FDIM;
    acc0 = acc0 * di + rowi[lane] * self;
    acc1 = acc1 * di + rowi[lane + 64] * self;
    float r0 = fmaxf(acc0 + b1[lane], 0.f) + x[(size_t)i * FDIM + lane];
    float r1 = fmaxf(acc1 + b1[lane + 64], 0.f) + x[(size_t)i * FDIM + lane + 64];
    z[(size_t)i * FDIM + lane] = r0;
    z[(size_t)i * FDIM + lane + 64] = r1;
}

// h2[i,:] = z[i,:] @ W2 ; one row per 64-thread block, lanes < C active for compute.
__global__ void gemm2_kernel(const float* __restrict__ z, const float* __restrict__ W,
                             float* __restrict__ h, int C) {
    __shared__ float zr[FDIM];
    int i = blockIdx.x;
    int t = threadIdx.x;
    zr[t] = z[(size_t)i * FDIM + t];
    zr[t + 64] = z[(size_t)i * FDIM + t + 64];
    __syncthreads();
    if (t < C) {
        float acc = 0.f;
#pragma unroll 8
        for (int k = 0; k < FDIM; ++k) acc += zr[k] * W[k * C + t];
        h[(size_t)i * C + t] = acc;
    }
}

// y[i,:] = dinv[i]*(sum_s h2[s,:]*dinv[s]) + h2[i,:]*dinv[i]^2 + b2
__global__ void agg2_kernel(const float* __restrict__ h2, const int* __restrict__ rowstart,
                            const int* __restrict__ adj, const float* __restrict__ dinv,
                            const float* __restrict__ b2, float* __restrict__ y,
                            int N, int C) {
    int wave = threadIdx.x >> 6;
    int lane = threadIdx.x & 63;
    int i = blockIdx.x * 4 + wave;
    if (i >= N) return;
    if (lane >= C) return;
    int s0 = rowstart[i], s1 = rowstart[i + 1];
    float acc = 0.f;
    for (int n = s0; n < s1; ++n) {
        int s = adj[n];
        acc += h2[(size_t)s * C + lane] * dinv[s];
    }
    float di = dinv[i];
    acc = acc * di + h2[(size_t)i * C + lane] * di * di + b2[lane];
    y[(size_t)i * C + lane] = acc;
}

extern "C" void kernel_launch(void* const* d_in, const int* in_sizes, int n_in,
                              void* d_out, int out_size, void* d_ws, size_t ws_size,
                              hipStream_t stream) {
    const float* x  = (const float*)d_in[0];
    const int*   ei = (const int*)d_in[1];   // int32 per harness integer convention
    const float* W1 = (const float*)d_in[2];
    const float* b1 = (const float*)d_in[3];
    const float* W2 = (const float*)d_in[4];
    const float* b2 = (const float*)d_in[5];
    float* y = (float*)d_out;

    const int H = in_sizes[3];           // 128
    const int C = in_sizes[5];           // 40
    const int F = in_sizes[2] / H;       // 128
    const int N = in_sizes[0] / F;       // 50000
    const int E = in_sizes[1] / 2;       // 800000
    (void)H; (void)ws_size; (void)n_in; (void)out_size;

    // Carve workspace (256B-aligned chunks).
    size_t off = 0;
    auto carve = [&](size_t bytes) -> void* {
        void* p = (char*)d_ws + off;
        off += (bytes + 255) & ~(size_t)255;
        return p;
    };
    int*   deg      = (int*)carve((size_t)N * 4);
    int*   rowstart = (int*)carve((size_t)(N + 1) * 4);
    int*   cursor   = (int*)carve((size_t)N * 4);
    float* dinv     = (float*)carve((size_t)N * 4);
    int*   adj      = (int*)carve((size_t)E * 4);
    float* h1       = (float*)carve((size_t)N * FDIM * 4);
    float* z        = (float*)carve((size_t)N * FDIM * 4);
    float* h2       = h1;  // h1 dead after agg1; reuse for layer-2 features

    hipMemsetAsync(deg, 0, (size_t)N * 4, stream);
    hipMemsetAsync(cursor, 0, (size_t)N * 4, stream);

    int eb = (E + 255) / 256;
    count_deg_kernel<<<eb, 256, 0, stream>>>(ei, E, deg);
    scan_kernel<<<1, 1024, 0, stream>>>(deg, rowstart, dinv, N);
    fill_adj_kernel<<<eb, 256, 0, stream>>>(ei, E, rowstart, cursor, adj);
    gemm1_kernel<<<N, 128, 0, stream>>>(x, W1, h1);
    agg1_kernel<<<(N + 3) / 4, 256, 0, stream>>>(h1, rowstart, adj, dinv, x, b1, z, N);
    gemm2_kernel<<<N, 64, 0, stream>>>(z, W2, h2, C);
    agg2_kernel<<<(N + 3) / 4, 256, 0, stream>>>(h2, rowstart, adj, dinv, b2, y, N, C);
}

// Round 2
// 376.981 us; speedup vs baseline: 1.4601x; 1.4601x over previous
//
#include <hip/hip_runtime.h>

// 2-layer GCN, pull-based (CSR) aggregation, fp32 throughout.
// count_deg -> scan(a,b,c) -> fill_adj -> gemm1(tiled) ->
// agg1(+bias,relu,residual) -> gemm2(tiled) -> agg2(+bias)->d_out

#define FDIM 128
#define GK 32   // K-chunk for tiled GEMMs

__global__ void count_deg_kernel(const int* __restrict__ ei, int E, int* __restrict__ deg) {
    int e = blockIdx.x * blockDim.x + threadIdx.x;
    if (e < E) atomicAdd(&deg[ei[E + e]], 1);
}

// ---- hierarchical scan: per-block local scan + block sums ----
__global__ void scan_a_kernel(const int* __restrict__ deg, int n,
                              int* __restrict__ rowstart, int* __restrict__ blocksum) {
    __shared__ int s[256];
    int t = threadIdx.x;
    int i = blockIdx.x * 256 + t;
    int v = (i < n) ? deg[i] : 0;
    s[t] = v;
    __syncthreads();
    for (int off = 1; off < 256; off <<= 1) {
        int tv = (t >= off) ? s[t - off] : 0;
        __syncthreads();
        s[t] += tv;
        __syncthreads();
    }
    if (i < n) rowstart[i] = s[t] - v;            // local exclusive
    if (t == 255) blocksum[blockIdx.x] = s[255];
}

// single block over <=256 block sums -> exclusive offsets; writes rowstart[n]=total
__global__ void scan_b_kernel(int* __restrict__ blocksum, int nb,
                              int* __restrict__ rowstart, int n) {
    __shared__ int s[256];
    int t = threadIdx.x;
    int v = (t < nb) ? blocksum[t] : 0;
    s[t] = v;
    __syncthreads();
    for (int off = 1; off < 256; off <<= 1) {
        int tv = (t >= off) ? s[t - off] : 0;
        __syncthreads();
        s[t] += tv;
        __syncthreads();
    }
    if (t < nb) blocksum[t] = s[t] - v;           // exclusive block offsets
    if (t == 0) rowstart[n] = s[255];             // total = E
}

__global__ void scan_c_kernel(const int* __restrict__ deg, int n,
                              const int* __restrict__ blocksum,
                              int* __restrict__ rowstart, float* __restrict__ dinv) {
    int i = blockIdx.x * 256 + threadIdx.x;
    if (i < n) {
        rowstart[i] += blocksum[blockIdx.x];
        dinv[i] = rsqrtf((float)(deg[i] + 1));    // +1 self-loop
    }
}

__global__ void fill_adj_kernel(const int* __restrict__ ei, int E,
                                const int* __restrict__ rowstart,
                                int* __restrict__ cursor, int* __restrict__ adj) {
    int e = blockIdx.x * blockDim.x + threadIdx.x;
    if (e >= E) return;
    int src = ei[e];
    int dst = ei[E + e];
    int pos = atomicAdd(&cursor[dst], 1);
    adj[rowstart[dst] + pos] = src;
}

// ---- tiled GEMM1: h[i,j] = sum_k x[i,k] * W[k,j], K=J=128 ----
// block: 128 rows x 128 cols; thread (tx=t&15, ty=t>>4): 8 rows x 8 cols.
// rows = {ty*4+a, 64+ty*4+a}; cols = {tx*4+c, 64+tx*4+c}  (conflict-light)
__launch_bounds__(256, 2)
__global__ void gemm1_tiled(const float* __restrict__ x, const float* __restrict__ W,
                            float* __restrict__ h, int N) {
    __shared__ float Ws[GK][128];       // 16 KB
    __shared__ float xs[GK][132];       // 16.9 KB (transposed [k][r], stride 132 keeps 16B align)
    int t = threadIdx.x;
    int tx = t & 15, ty = t >> 4;
    int i0 = blockIdx.x * 128;

    float acc[8][8];
#pragma unroll
    for (int a = 0; a < 8; ++a)
#pragma unroll
        for (int b = 0; b < 8; ++b) acc[a][b] = 0.f;

    for (int kb = 0; kb < FDIM / GK; ++kb) {
        __syncthreads();
        // stage W chunk: [GK][128] = 1024 float4
        for (int p = t; p < 1024; p += 256) {
            float4 v = *(const float4*)(W + (size_t)(kb * GK + (p >> 5)) * 128 + ((p & 31) * 4));
            *(float4*)&Ws[p >> 5][(p & 31) * 4] = v;
        }
        // stage x chunk transposed: thread loads float4 along k, scatters to xs[k][r]
        int kq = (t & 7) * 4;           // k_local base
        int rb = t >> 3;                // 0..31
#pragma unroll
        for (int pass = 0; pass < 4; ++pass) {
            int r = pass * 32 + rb;
            int row = i0 + r;
            float4 v = make_float4(0.f, 0.f, 0.f, 0.f);
            if (row < N) v = *(const float4*)(x + (size_t)row * FDIM + kb * GK + kq);
            xs[kq + 0][r] = v.x;
            xs[kq + 1][r] = v.y;
            xs[kq + 2][r] = v.z;
            xs[kq + 3][r] = v.w;
        }
        __syncthreads();
#pragma unroll 4
        for (int k = 0; k < GK; ++k) {
            float4 a0 = *(const float4*)&xs[k][ty * 4];
            float4 a1 = *(const float4*)&xs[k][64 + ty * 4];
            float4 b0 = *(const float4*)&Ws[k][tx * 4];
            float4 b1 = *(const float4*)&Ws[k][64 + tx * 4];
            float av[8] = {a0.x, a0.y, a0.z, a0.w, a1.x, a1.y, a1.z, a1.w};
            float bv[8] = {b0.x, b0.y, b0.z, b0.w, b1.x, b1.y, b1.z, b1.w};
#pragma unroll
            for (int a = 0; a < 8; ++a)
#pragma unroll
                for (int b = 0; b < 8; ++b) acc[a][b] += av[a] * bv[b];
        }
    }
    // store
#pragma unroll
    for (int g = 0; g < 2; ++g)
#pragma unroll
        for (int a = 0; a < 4; ++a) {
            int row = i0 + g * 64 + ty * 4 + a;
            if (row < N) {
                int ri = g * 4 + a;
                *(float4*)(h + (size_t)row * FDIM + tx * 4) =
                    make_float4(acc[ri][0], acc[ri][1], acc[ri][2], acc[ri][3]);
                *(float4*)(h + (size_t)row * FDIM + 64 + tx * 4) =
                    make_float4(acc[ri][4], acc[ri][5], acc[ri][6], acc[ri][7]);
            }
        }
}

// z[i,:] = relu( dinv[i]*(sum_s h1[s,:]*dinv[s] + h1[i,:]*dinv[i]) + b1 ) + x[i,:]
__global__ void agg1_kernel(const float* __restrict__ h1, const int* __restrict__ rowstart,
                            const int* __restrict__ adj, const float* __restrict__ dinv,
                            const float* __restrict__ x, const float* __restrict__ b1,
                            float* __restrict__ z, int N) {
    int wave = threadIdx.x >> 6;
    int lane = threadIdx.x & 63;
    int i = blockIdx.x * 4 + wave;
    if (i >= N) return;
    int s0 = rowstart[i], s1 = rowstart[i + 1];
    float ax = 0.f, ay = 0.f;
    int n = s0;
    for (; n + 1 < s1; n += 2) {
        int sa = adj[n], sb = adj[n + 1];
        float wa = dinv[sa], wb = dinv[sb];
        float2 ra = ((const float2*)(h1 + (size_t)sa * FDIM))[lane];
        float2 rb = ((const float2*)(h1 + (size_t)sb * FDIM))[lane];
        ax += ra.x * wa + rb.x * wb;
        ay += ra.y * wa + rb.y * wb;
    }
    if (n < s1) {
        int sa = adj[n];
        float wa = dinv[sa];
        float2 ra = ((const float2*)(h1 + (size_t)sa * FDIM))[lane];
        ax += ra.x * wa;
        ay += ra.y * wa;
    }
    float di = dinv[i];
    float self = di * di;
    float2 hi = ((const float2*)(h1 + (size_t)i * FDIM))[lane];
    ax = ax * di + hi.x * self;
    ay = ay * di + hi.y * self;
    float2 bb = ((const float2*)b1)[lane];
    float2 xi = ((const float2*)(x + (size_t)i * FDIM))[lane];
    float2 res;
    res.x = fmaxf(ax + bb.x, 0.f) + xi.x;
    res.y = fmaxf(ay + bb.y, 0.f) + xi.y;
    ((float2*)(z + (size_t)i * FDIM))[lane] = res;
}

// ---- tiled GEMM2: h2[i,j] = sum_k z[i,k]*W2[k,j], J=40 padded to 64 (stride 64 out) ----
__launch_bounds__(256, 2)
__global__ void gemm2_tiled(const float* __restrict__ z, const float* __restrict__ W2,
                            float* __restrict__ h2, int N) {
    __shared__ float Ws[GK][64];        // 8 KB (cols 40..63 zero)
    __shared__ float zs[GK][132];       // 16.9 KB
    int t = threadIdx.x;
    int tx = t & 15, ty = t >> 4;
    int i0 = blockIdx.x * 128;

    float acc[8][4];
#pragma unroll
    for (int a = 0; a < 8; ++a)
#pragma unroll
        for (int b = 0; b < 4; ++b) acc[a][b] = 0.f;

    for (int kb = 0; kb < FDIM / GK; ++kb) {
        __syncthreads();
        for (int p = t; p < GK * 64; p += 256) {
            int k = p >> 6, j = p & 63;
            Ws[k][j] = (j < 40) ? W2[(size_t)(kb * GK + k) * 40 + j] : 0.f;
        }
        int kq = (t & 7) * 4;
        int rb = t >> 3;
#pragma unroll
        for (int pass = 0; pass < 4; ++pass) {
            int r = pass * 32 + rb;
            int row = i0 + r;
            float4 v = make_float4(0.f, 0.f, 0.f, 0.f);
            if (row < N) v = *(const float4*)(z + (size_t)row * FDIM + kb * GK + kq);
            zs[kq + 0][r] = v.x;
            zs[kq + 1][r] = v.y;
            zs[kq + 2][r] = v.z;
            zs[kq + 3][r] = v.w;
        }
        __syncthreads();
#pragma unroll 4
        for (int k = 0; k < GK; ++k) {
            float4 a0 = *(const float4*)&zs[k][ty * 4];
            float4 a1 = *(const float4*)&zs[k][64 + ty * 4];
            float4 b0 = *(const float4*)&Ws[k][tx * 4];
            float av[8] = {a0.x, a0.y, a0.z, a0.w, a1.x, a1.y, a1.z, a1.w};
            float bv[4] = {b0.x, b0.y, b0.z, b0.w};
#pragma unroll
            for (int a = 0; a < 8; ++a)
#pragma unroll
                for (int b = 0; b < 4; ++b) acc[a][b] += av[a] * bv[b];
        }
    }
    if (tx < 10) {  // cols tx*4 .. tx*4+3 all < 40
#pragma unroll
        for (int g = 0; g < 2; ++g)
#pragma unroll
            for (int a = 0; a < 4; ++a) {
                int row = i0 + g * 64 + ty * 4 + a;
                if (row < N) {
                    int ri = g * 4 + a;
                    *(float4*)(h2 + (size_t)row * 64 + tx * 4) =
                        make_float4(acc[ri][0], acc[ri][1], acc[ri][2], acc[ri][3]);
                }
            }
    }
}

// y[i,:] = dinv[i]*(sum_s h2[s,:]*dinv[s] + h2[i,:]*dinv[i]) + b2 ; h2 stride 64, y stride 40
__global__ void agg2_kernel(const float* __restrict__ h2, const int* __restrict__ rowstart,
                            const int* __restrict__ adj, const float* __restrict__ dinv,
                            const float* __restrict__ b2, float* __restrict__ y, int N) {
    int wave = threadIdx.x >> 6;
    int lane = threadIdx.x & 63;
    int i = blockIdx.x * 4 + wave;
    if (i >= N) return;
    if (lane >= 20) return;   // 20 lanes x float2 = 40 cols
    int s0 = rowstart[i], s1 = rowstart[i + 1];
    float ax = 0.f, ay = 0.f;
    int n = s0;
    for (; n + 1 < s1; n += 2) {
        int sa = adj[n], sb = adj[n + 1];
        float wa = dinv[sa], wb = dinv[sb];
        float2 ra = ((const float2*)(h2 + (size_t)sa * 64))[lane];
        float2 rb = ((const float2*)(h2 + (size_t)sb * 64))[lane];
        ax += ra.x * wa + rb.x * wb;
        ay += ra.y * wa + rb.y * wb;
    }
    if (n < s1) {
        int sa = adj[n];
        float wa = dinv[sa];
        float2 ra = ((const float2*)(h2 + (size_t)sa * 64))[lane];
        ax += ra.x * wa;
        ay += ra.y * wa;
    }
    float di = dinv[i];
    float2 hi = ((const float2*)(h2 + (size_t)i * 64))[lane];
    float2 bb = ((const float2*)b2)[lane];
    float2 res;
    res.x = ax * di + hi.x * di * di + bb.x;
    res.y = ay * di + hi.y * di * di + bb.y;
    ((float2*)(y + (size_t)i * 40))[lane] = res;
}

extern "C" void kernel_launch(void* const* d_in, const int* in_sizes, int n_in,
                              void* d_out, int out_size, void* d_ws, size_t ws_size,
                              hipStream_t stream) {
    const float* x  = (const float*)d_in[0];
    const int*   ei = (const int*)d_in[1];
    const float* W1 = (const float*)d_in[2];
    const float* b1 = (const float*)d_in[3];
    const float* W2 = (const float*)d_in[4];
    const float* b2 = (const float*)d_in[5];
    float* y = (float*)d_out;

    const int H = in_sizes[3];           // 128
    const int F = in_sizes[2] / H;       // 128
    const int N = in_sizes[0] / F;       // 50000
    const int E = in_sizes[1] / 2;       // 800000
    (void)H; (void)ws_size; (void)n_in; (void)out_size;

    size_t off = 0;
    auto carve = [&](size_t bytes) -> void* {
        void* p = (char*)d_ws + off;
        off += (bytes + 255) & ~(size_t)255;
        return p;
    };
    int*   deg      = (int*)carve((size_t)N * 4);
    int*   rowstart = (int*)carve((size_t)(N + 1) * 4);
    int*   cursor   = (int*)carve((size_t)N * 4);
    float* dinv     = (float*)carve((size_t)N * 4);
    int*   blocksum = (int*)carve(256 * 4);
    int*   adj      = (int*)carve((size_t)E * 4);
    float* h1       = (float*)carve((size_t)N * FDIM * 4);
    float* z        = (float*)carve((size_t)N * FDIM * 4);
    float* h2       = h1;  // h1 dead after agg1; h2 is N x 64 (fits in h1's N x 128)

    hipMemsetAsync(deg, 0, (size_t)N * 4, stream);
    hipMemsetAsync(cursor, 0, (size_t)N * 4, stream);

    int eb = (E + 255) / 256;
    int nbs = (N + 255) / 256;   // 196 (<=256 required by scan_b)
    count_deg_kernel<<<eb, 256, 0, stream>>>(ei, E, deg);
    scan_a_kernel<<<nbs, 256, 0, stream>>>(deg, N, rowstart, blocksum);
    scan_b_kernel<<<1, 256, 0, stream>>>(blocksum, nbs, rowstart, N);
    scan_c_kernel<<<nbs, 256, 0, stream>>>(deg, N, blocksum, rowstart, dinv);
    fill_adj_kernel<<<eb, 256, 0, stream>>>(ei, E, rowstart, cursor, adj);

    int nbt = (N + 127) / 128;   // 391 tile blocks
    gemm1_tiled<<<nbt, 256, 0, stream>>>(x, W1, h1, N);
    agg1_kernel<<<(N + 3) / 4, 256, 0, stream>>>(h1, rowstart, adj, dinv, x, b1, z, N);
    gemm2_tiled<<<nbt, 256, 0, stream>>>(z, W2, h2, N);
    agg2_kernel<<<(N + 3) / 4, 256, 0, stream>>>(h2, rowstart, adj, dinv, b2, y, N);
}

// Round 3
// 296.478 us; speedup vs baseline: 1.8565x; 1.2715x over previous
//
#include <hip/hip_runtime.h>
#include <hip/hip_fp16.h>

// 2-layer GCN, pull-based (CSR) aggregation. fp32 math, fp16 post-GEMM
// intermediates (h1, h2) to halve gather traffic in the aggregates.
// count_deg -> scan(a,b,c) -> fill_adj -> gemm1(tiled,fp16 out) ->
// agg1(+bias,relu,residual) -> gemm2(tiled,fp16 out) -> agg2(+bias)->d_out

#define FDIM 128
#define GK 32   // K-chunk for tiled GEMMs

__global__ void count_deg_kernel(const int* __restrict__ ei, int E, int* __restrict__ deg) {
    int e = blockIdx.x * blockDim.x + threadIdx.x;
    if (e < E) atomicAdd(&deg[ei[E + e]], 1);
}

// ---- hierarchical scan ----
__global__ void scan_a_kernel(const int* __restrict__ deg, int n,
                              int* __restrict__ rowstart, int* __restrict__ blocksum) {
    __shared__ int s[256];
    int t = threadIdx.x;
    int i = blockIdx.x * 256 + t;
    int v = (i < n) ? deg[i] : 0;
    s[t] = v;
    __syncthreads();
    for (int off = 1; off < 256; off <<= 1) {
        int tv = (t >= off) ? s[t - off] : 0;
        __syncthreads();
        s[t] += tv;
        __syncthreads();
    }
    if (i < n) rowstart[i] = s[t] - v;
    if (t == 255) blocksum[blockIdx.x] = s[255];
}

__global__ void scan_b_kernel(int* __restrict__ blocksum, int nb,
                              int* __restrict__ rowstart, int n) {
    __shared__ int s[256];
    int t = threadIdx.x;
    int v = (t < nb) ? blocksum[t] : 0;
    s[t] = v;
    __syncthreads();
    for (int off = 1; off < 256; off <<= 1) {
        int tv = (t >= off) ? s[t - off] : 0;
        __syncthreads();
        s[t] += tv;
        __syncthreads();
    }
    if (t < nb) blocksum[t] = s[t] - v;
    if (t == 0) rowstart[n] = s[255];
}

__global__ void scan_c_kernel(const int* __restrict__ deg, int n,
                              const int* __restrict__ blocksum,
                              int* __restrict__ rowstart, float* __restrict__ dinv) {
    int i = blockIdx.x * 256 + threadIdx.x;
    if (i < n) {
        rowstart[i] += blocksum[blockIdx.x];
        dinv[i] = rsqrtf((float)(deg[i] + 1));
    }
}

__global__ void fill_adj_kernel(const int* __restrict__ ei, int E,
                                const int* __restrict__ rowstart,
                                int* __restrict__ cursor, int* __restrict__ adj) {
    int e = blockIdx.x * blockDim.x + threadIdx.x;
    if (e >= E) return;
    int src = ei[e];
    int dst = ei[E + e];
    int pos = atomicAdd(&cursor[dst], 1);
    adj[rowstart[dst] + pos] = src;
}

// ---- tiled GEMM1: h1 = x @ W1 (fp16 out), 128x128 block, 8x8/thread ----
__launch_bounds__(256, 2)
__global__ void gemm1_tiled(const float* __restrict__ x, const float* __restrict__ W,
                            __half* __restrict__ h, int N) {
    __shared__ float Ws[GK][128];
    __shared__ float xs[GK][132];
    int t = threadIdx.x;
    int tx = t & 15, ty = t >> 4;
    int i0 = blockIdx.x * 128;

    float acc[8][8];
#pragma unroll
    for (int a = 0; a < 8; ++a)
#pragma unroll
        for (int b = 0; b < 8; ++b) acc[a][b] = 0.f;

    for (int kb = 0; kb < FDIM / GK; ++kb) {
        __syncthreads();
        for (int p = t; p < 1024; p += 256) {
            float4 v = *(const float4*)(W + (size_t)(kb * GK + (p >> 5)) * 128 + ((p & 31) * 4));
            *(float4*)&Ws[p >> 5][(p & 31) * 4] = v;
        }
        int kq = (t & 7) * 4;
        int rb = t >> 3;
#pragma unroll
        for (int pass = 0; pass < 4; ++pass) {
            int r = pass * 32 + rb;
            int row = i0 + r;
            float4 v = make_float4(0.f, 0.f, 0.f, 0.f);
            if (row < N) v = *(const float4*)(x + (size_t)row * FDIM + kb * GK + kq);
            xs[kq + 0][r] = v.x;
            xs[kq + 1][r] = v.y;
            xs[kq + 2][r] = v.z;
            xs[kq + 3][r] = v.w;
        }
        __syncthreads();
#pragma unroll 4
        for (int k = 0; k < GK; ++k) {
            float4 a0 = *(const float4*)&xs[k][ty * 4];
            float4 a1 = *(const float4*)&xs[k][64 + ty * 4];
            float4 b0 = *(const float4*)&Ws[k][tx * 4];
            float4 b1 = *(const float4*)&Ws[k][64 + tx * 4];
            float av[8] = {a0.x, a0.y, a0.z, a0.w, a1.x, a1.y, a1.z, a1.w};
            float bv[8] = {b0.x, b0.y, b0.z, b0.w, b1.x, b1.y, b1.z, b1.w};
#pragma unroll
            for (int a = 0; a < 8; ++a)
#pragma unroll
                for (int b = 0; b < 8; ++b) acc[a][b] += av[a] * bv[b];
        }
    }
#pragma unroll
    for (int g = 0; g < 2; ++g)
#pragma unroll
        for (int a = 0; a < 4; ++a) {
            int row = i0 + g * 64 + ty * 4 + a;
            if (row < N) {
                int ri = g * 4 + a;
                union { __half2 hh[2]; float2 f; } u0, u1;
                u0.hh[0] = __floats2half2_rn(acc[ri][0], acc[ri][1]);
                u0.hh[1] = __floats2half2_rn(acc[ri][2], acc[ri][3]);
                u1.hh[0] = __floats2half2_rn(acc[ri][4], acc[ri][5]);
                u1.hh[1] = __floats2half2_rn(acc[ri][6], acc[ri][7]);
                *(float2*)(h + (size_t)row * FDIM + tx * 4) = u0.f;
                *(float2*)(h + (size_t)row * FDIM + 64 + tx * 4) = u1.f;
            }
        }
}

// z[i,:] = relu( dinv[i]*(sum_s h1[s,:]*dinv[s] + h1[i,:]*dinv[i]) + b1 ) + x[i,:]
// one wave per node; lane covers 2 feats (half2); 4 edges in flight.
__global__ void agg1_kernel(const __half* __restrict__ h1, const int* __restrict__ rowstart,
                            const int* __restrict__ adj, const float* __restrict__ dinv,
                            const float* __restrict__ x, const float* __restrict__ b1,
                            float* __restrict__ z, int N) {
    int wave = threadIdx.x >> 6;
    int lane = threadIdx.x & 63;
    int i = blockIdx.x * 4 + wave;
    if (i >= N) return;
    int s0 = rowstart[i], s1 = rowstart[i + 1];
    float ax = 0.f, ay = 0.f;
    int n = s0;
    for (; n + 3 < s1; n += 4) {
        int sa = adj[n], sb = adj[n + 1], sc = adj[n + 2], sd = adj[n + 3];
        float wa = dinv[sa], wb = dinv[sb], wc = dinv[sc], wd = dinv[sd];
        float2 ra = __half22float2(((const __half2*)(h1 + (size_t)sa * FDIM))[lane]);
        float2 rb = __half22float2(((const __half2*)(h1 + (size_t)sb * FDIM))[lane]);
        float2 rc = __half22float2(((const __half2*)(h1 + (size_t)sc * FDIM))[lane]);
        float2 rd = __half22float2(((const __half2*)(h1 + (size_t)sd * FDIM))[lane]);
        ax += ra.x * wa + rb.x * wb + rc.x * wc + rd.x * wd;
        ay += ra.y * wa + rb.y * wb + rc.y * wc + rd.y * wd;
    }
    for (; n < s1; ++n) {
        int sa = adj[n];
        float wa = dinv[sa];
        float2 ra = __half22float2(((const __half2*)(h1 + (size_t)sa * FDIM))[lane]);
        ax += ra.x * wa;
        ay += ra.y * wa;
    }
    float di = dinv[i];
    float self = di * di;
    float2 hi = __half22float2(((const __half2*)(h1 + (size_t)i * FDIM))[lane]);
    ax = ax * di + hi.x * self;
    ay = ay * di + hi.y * self;
    float2 bb = ((const float2*)b1)[lane];
    float2 xi = ((const float2*)(x + (size_t)i * FDIM))[lane];
    float2 res;
    res.x = fmaxf(ax + bb.x, 0.f) + xi.x;
    res.y = fmaxf(ay + bb.y, 0.f) + xi.y;
    ((float2*)(z + (size_t)i * FDIM))[lane] = res;
}

// ---- tiled GEMM2: h2 = z @ W2 (fp16 out, dense stride 40) ----
__launch_bounds__(256, 2)
__global__ void gemm2_tiled(const float* __restrict__ z, const float* __restrict__ W2,
                            __half* __restrict__ h2, int N) {
    __shared__ float Ws[GK][64];
    __shared__ float zs[GK][132];
    int t = threadIdx.x;
    int tx = t & 15, ty = t >> 4;
    int i0 = blockIdx.x * 128;

    float acc[8][4];
#pragma unroll
    for (int a = 0; a < 8; ++a)
#pragma unroll
        for (int b = 0; b < 4; ++b) acc[a][b] = 0.f;

    for (int kb = 0; kb < FDIM / GK; ++kb) {
        __syncthreads();
        for (int p = t; p < GK * 64; p += 256) {
            int k = p >> 6, j = p & 63;
            Ws[k][j] = (j < 40) ? W2[(size_t)(kb * GK + k) * 40 + j] : 0.f;
        }
        int kq = (t & 7) * 4;
        int rb = t >> 3;
#pragma unroll
        for (int pass = 0; pass < 4; ++pass) {
            int r = pass * 32 + rb;
            int row = i0 + r;
            float4 v = make_float4(0.f, 0.f, 0.f, 0.f);
            if (row < N) v = *(const float4*)(z + (size_t)row * FDIM + kb * GK + kq);
            zs[kq + 0][r] = v.x;
            zs[kq + 1][r] = v.y;
            zs[kq + 2][r] = v.z;
            zs[kq + 3][r] = v.w;
        }
        __syncthreads();
#pragma unroll 4
        for (int k = 0; k < GK; ++k) {
            float4 a0 = *(const float4*)&zs[k][ty * 4];
            float4 a1 = *(const float4*)&zs[k][64 + ty * 4];
            float4 b0 = *(const float4*)&Ws[k][tx * 4];
            float av[8] = {a0.x, a0.y, a0.z, a0.w, a1.x, a1.y, a1.z, a1.w};
            float bv[4] = {b0.x, b0.y, b0.z, b0.w};
#pragma unroll
            for (int a = 0; a < 8; ++a)
#pragma unroll
                for (int b = 0; b < 4; ++b) acc[a][b] += av[a] * bv[b];
        }
    }
    if (tx < 10) {
#pragma unroll
        for (int g = 0; g < 2; ++g)
#pragma unroll
            for (int a = 0; a < 4; ++a) {
                int row = i0 + g * 64 + ty * 4 + a;
                if (row < N) {
                    int ri = g * 4 + a;
                    union { __half2 hh[2]; float2 f; } u;
                    u.hh[0] = __floats2half2_rn(acc[ri][0], acc[ri][1]);
                    u.hh[1] = __floats2half2_rn(acc[ri][2], acc[ri][3]);
                    *(float2*)(h2 + (size_t)row * 40 + tx * 4) = u.f;
                }
            }
    }
}

// y[i,:] = dinv[i]*(sum_s h2[s,:]*dinv[s] + h2[i,:]*dinv[i]) + b2
// wave per node; 3 edge-groups x 20 lanes (feats as half2), shfl-reduce.
__global__ void agg2_kernel(const __half* __restrict__ h2, const int* __restrict__ rowstart,
                            const int* __restrict__ adj, const float* __restrict__ dinv,
                            const float* __restrict__ b2, float* __restrict__ y, int N) {
    int wave = threadIdx.x >> 6;
    int lane = threadIdx.x & 63;
    int i = blockIdx.x * 4 + wave;
    if (i >= N) return;
    int e = (lane >= 40) ? 2 : ((lane >= 20) ? 1 : 0);
    int f = lane - 20 * e;
    int s0 = rowstart[i], s1 = rowstart[i + 1];
    float ax = 0.f, ay = 0.f;
    if (lane < 60) {
        int n = s0 + e;
        for (; n + 3 < s1; n += 6) {   // 2 edges per group per iter
            int sa = adj[n], sb = adj[n + 3];
            float wa = dinv[sa], wb = dinv[sb];
            float2 ra = __half22float2(((const __half2*)(h2 + (size_t)sa * 40))[f]);
            float2 rb = __half22float2(((const __half2*)(h2 + (size_t)sb * 40))[f]);
            ax += ra.x * wa + rb.x * wb;
            ay += ra.y * wa + rb.y * wb;
        }
        if (n < s1) {
            int sa = adj[n];
            float wa = dinv[sa];
            float2 ra = __half22float2(((const __half2*)(h2 + (size_t)sa * 40))[f]);
            ax += ra.x * wa;
            ay += ra.y * wa;
        }
    }
    // fold groups 1,2 into group 0 (results consumed only on lanes < 20)
    float sx = ax + __shfl(ax, lane + 20, 64) + __shfl(ax, lane + 40, 64);
    float sy = ay + __shfl(ay, lane + 20, 64) + __shfl(ay, lane + 40, 64);
    if (lane < 20) {
        float di = dinv[i];
        float2 hi = __half22float2(((const __half2*)(h2 + (size_t)i * 40))[lane]);
        float2 bb = ((const float2*)b2)[lane];
        float2 res;
        res.x = sx * di + hi.x * di * di + bb.x;
        res.y = sy * di + hi.y * di * di + bb.y;
        ((float2*)(y + (size_t)i * 40))[lane] = res;
    }
}

extern "C" void kernel_launch(void* const* d_in, const int* in_sizes, int n_in,
                              void* d_out, int out_size, void* d_ws, size_t ws_size,
                              hipStream_t stream) {
    const float* x  = (const float*)d_in[0];
    const int*   ei = (const int*)d_in[1];
    const float* W1 = (const float*)d_in[2];
    const float* b1 = (const float*)d_in[3];
    const float* W2 = (const float*)d_in[4];
    const float* b2 = (const float*)d_in[5];
    float* y = (float*)d_out;

    const int H = in_sizes[3];           // 128
    const int F = in_sizes[2] / H;       // 128
    const int N = in_sizes[0] / F;       // 50000
    const int E = in_sizes[1] / 2;       // 800000
    (void)H; (void)ws_size; (void)n_in; (void)out_size;

    size_t off = 0;
    auto carve = [&](size_t bytes) -> void* {
        void* p = (char*)d_ws + off;
        off += (bytes + 255) & ~(size_t)255;
        return p;
    };
    int*    deg      = (int*)carve((size_t)N * 4);
    int*    rowstart = (int*)carve((size_t)(N + 1) * 4);
    int*    cursor   = (int*)carve((size_t)N * 4);
    float*  dinv     = (float*)carve((size_t)N * 4);
    int*    blocksum = (int*)carve(256 * 4);
    int*    adj      = (int*)carve((size_t)E * 4);
    __half* h1       = (__half*)carve((size_t)N * FDIM * 2);
    float*  z        = (float*)carve((size_t)N * FDIM * 4);
    __half* h2       = h1;   // h1 dead after agg1; h2 is N x 40 fp16 (fits)

    hipMemsetAsync(deg, 0, (size_t)N * 4, stream);
    hipMemsetAsync(cursor, 0, (size_t)N * 4, stream);

    int eb = (E + 255) / 256;
    int nbs = (N + 255) / 256;
    count_deg_kernel<<<eb, 256, 0, stream>>>(ei, E, deg);
    scan_a_kernel<<<nbs, 256, 0, stream>>>(deg, N, rowstart, blocksum);
    scan_b_kernel<<<1, 256, 0, stream>>>(blocksum, nbs, rowstart, N);
    scan_c_kernel<<<nbs, 256, 0, stream>>>(deg, N, blocksum, rowstart, dinv);
    fill_adj_kernel<<<eb, 256, 0, stream>>>(ei, E, rowstart, cursor, adj);

    int nbt = (N + 127) / 128;
    gemm1_tiled<<<nbt, 256, 0, stream>>>(x, W1, h1, N);
    agg1_kernel<<<(N + 3) / 4, 256, 0, stream>>>(h1, rowstart, adj, dinv, x, b1, z, N);
    gemm2_tiled<<<nbt, 256, 0, stream>>>(z, W2, h2, N);
    agg2_kernel<<<(N + 3) / 4, 256, 0, stream>>>(h2, rowstart, adj, dinv, b2, y, N);
}

// Round 4
// 283.987 us; speedup vs baseline: 1.9382x; 1.0440x over previous
//
#include <hip/hip_runtime.h>
#include <hip/hip_fp16.h>

// 2-layer GCN, pull-based (CSR) aggregation. fp32 math, fp16 intermediates
// (h1, z, h2) to halve gather/GEMM traffic. Aggregates are gather-latency
// bound -> deep manual unroll for memory-level parallelism.
// memset -> count_deg(int4) -> scan_a(+dinv) -> scan_bc -> fill_adj(int4) ->
// gemm1(f32 in, f16 out) -> agg1(8-unroll, f16 z) -> gemm2(f16 in/out) ->
// agg2(3x20 lanes, 4-unroll) -> d_out

#define FDIM 128
#define GK 32

__global__ void count_deg_kernel(const int* __restrict__ ei, int E, int* __restrict__ deg) {
    int idx = blockIdx.x * blockDim.x + threadIdx.x;
    int e4 = idx * 4;
    if (e4 + 3 < E) {
        int d0 = ei[E + e4], d1 = ei[E + e4 + 1], d2 = ei[E + e4 + 2], d3 = ei[E + e4 + 3];
        atomicAdd(&deg[d0], 1);
        atomicAdd(&deg[d1], 1);
        atomicAdd(&deg[d2], 1);
        atomicAdd(&deg[d3], 1);
    } else {
        for (int e = e4; e < E; ++e) atomicAdd(&deg[ei[E + e]], 1);
    }
}

// local exclusive scan per 256-block, block sums out, dinv = rsqrt(deg+1)
__global__ void scan_a_kernel(const int* __restrict__ deg, int n,
                              int* __restrict__ rowstart, int* __restrict__ blocksum,
                              float* __restrict__ dinv) {
    __shared__ int s[256];
    int t = threadIdx.x;
    int i = blockIdx.x * 256 + t;
    int v = (i < n) ? deg[i] : 0;
    s[t] = v;
    __syncthreads();
    for (int off = 1; off < 256; off <<= 1) {
        int tv = (t >= off) ? s[t - off] : 0;
        __syncthreads();
        s[t] += tv;
        __syncthreads();
    }
    if (i < n) {
        rowstart[i] = s[t] - v;
        dinv[i] = rsqrtf((float)(v + 1));
    }
    if (t == 255) blocksum[blockIdx.x] = s[255];
}

// every block scans blocksum (nb<=256) redundantly, applies its offset
__global__ void scan_bc_kernel(int n, const int* __restrict__ blocksum, int nb,
                               int* __restrict__ rowstart) {
    __shared__ int s[256];
    int t = threadIdx.x;
    s[t] = (t < nb) ? blocksum[t] : 0;
    __syncthreads();
    for (int off = 1; off < 256; off <<= 1) {
        int tv = (t >= off) ? s[t - off] : 0;
        __syncthreads();
        s[t] += tv;
        __syncthreads();
    }
    int myoff = (blockIdx.x == 0) ? 0 : s[blockIdx.x - 1];   // inclusive scan -> excl offset
    int i = blockIdx.x * 256 + t;
    if (i < n) rowstart[i] += myoff;
    if (blockIdx.x == 0 && t == 0) rowstart[n] = s[255];     // total = E
}

__global__ void fill_adj_kernel(const int* __restrict__ ei, int E,
                                const int* __restrict__ rowstart,
                                int* __restrict__ cursor, int* __restrict__ adj) {
    int idx = blockIdx.x * blockDim.x + threadIdx.x;
    int e4 = idx * 4;
    if (e4 + 3 < E) {
        int4 sv = *(const int4*)(ei + e4);
        int d0 = ei[E + e4], d1 = ei[E + e4 + 1], d2 = ei[E + e4 + 2], d3 = ei[E + e4 + 3];
        adj[rowstart[d0] + atomicAdd(&cursor[d0], 1)] = sv.x;
        adj[rowstart[d1] + atomicAdd(&cursor[d1], 1)] = sv.y;
        adj[rowstart[d2] + atomicAdd(&cursor[d2], 1)] = sv.z;
        adj[rowstart[d3] + atomicAdd(&cursor[d3], 1)] = sv.w;
    } else {
        for (int e = e4; e < E; ++e) {
            int src = ei[e];
            int dst = ei[E + e];
            adj[rowstart[dst] + atomicAdd(&cursor[dst], 1)] = src;
        }
    }
}

// ---- tiled GEMM1: h1 = x @ W1 (fp16 out), 128x128 block, 8x8/thread ----
__launch_bounds__(256, 2)
__global__ void gemm1_tiled(const float* __restrict__ x, const float* __restrict__ W,
                            __half* __restrict__ h, int N) {
    __shared__ float Ws[GK][128];
    __shared__ float xs[GK][132];
    int t = threadIdx.x;
    int tx = t & 15, ty = t >> 4;
    int i0 = blockIdx.x * 128;

    float acc[8][8];
#pragma unroll
    for (int a = 0; a < 8; ++a)
#pragma unroll
        for (int b = 0; b < 8; ++b) acc[a][b] = 0.f;

    for (int kb = 0; kb < FDIM / GK; ++kb) {
        __syncthreads();
        for (int p = t; p < 1024; p += 256) {
            float4 v = *(const float4*)(W + (size_t)(kb * GK + (p >> 5)) * 128 + ((p & 31) * 4));
            *(float4*)&Ws[p >> 5][(p & 31) * 4] = v;
        }
        int kq = (t & 7) * 4;
        int rb = t >> 3;
#pragma unroll
        for (int pass = 0; pass < 4; ++pass) {
            int r = pass * 32 + rb;
            int row = i0 + r;
            float4 v = make_float4(0.f, 0.f, 0.f, 0.f);
            if (row < N) v = *(const float4*)(x + (size_t)row * FDIM + kb * GK + kq);
            xs[kq + 0][r] = v.x;
            xs[kq + 1][r] = v.y;
            xs[kq + 2][r] = v.z;
            xs[kq + 3][r] = v.w;
        }
        __syncthreads();
#pragma unroll 4
        for (int k = 0; k < GK; ++k) {
            float4 a0 = *(const float4*)&xs[k][ty * 4];
            float4 a1 = *(const float4*)&xs[k][64 + ty * 4];
            float4 b0 = *(const float4*)&Ws[k][tx * 4];
            float4 b1 = *(const float4*)&Ws[k][64 + tx * 4];
            float av[8] = {a0.x, a0.y, a0.z, a0.w, a1.x, a1.y, a1.z, a1.w};
            float bv[8] = {b0.x, b0.y, b0.z, b0.w, b1.x, b1.y, b1.z, b1.w};
#pragma unroll
            for (int a = 0; a < 8; ++a)
#pragma unroll
                for (int b = 0; b < 8; ++b) acc[a][b] += av[a] * bv[b];
        }
    }
#pragma unroll
    for (int g = 0; g < 2; ++g)
#pragma unroll
        for (int a = 0; a < 4; ++a) {
            int row = i0 + g * 64 + ty * 4 + a;
            if (row < N) {
                int ri = g * 4 + a;
                union { __half2 hh[2]; float2 f; } u0, u1;
                u0.hh[0] = __floats2half2_rn(acc[ri][0], acc[ri][1]);
                u0.hh[1] = __floats2half2_rn(acc[ri][2], acc[ri][3]);
                u1.hh[0] = __floats2half2_rn(acc[ri][4], acc[ri][5]);
                u1.hh[1] = __floats2half2_rn(acc[ri][6], acc[ri][7]);
                *(float2*)(h + (size_t)row * FDIM + tx * 4) = u0.f;
                *(float2*)(h + (size_t)row * FDIM + 64 + tx * 4) = u1.f;
            }
        }
}

// z[i,:] = relu( dinv[i]*(sum_s h1[s,:]*dinv[s] + h1[i,:]*dinv[i]) + b1 ) + x[i,:]
// one wave per node; lane = 2 feats (half2); 8 gathers in flight.
__global__ void agg1_kernel(const __half* __restrict__ h1, const int* __restrict__ rowstart,
                            const int* __restrict__ adj, const float* __restrict__ dinv,
                            const float* __restrict__ x, const float* __restrict__ b1,
                            __half* __restrict__ z, int N) {
    int wave = threadIdx.x >> 6;
    int lane = threadIdx.x & 63;
    int i = blockIdx.x * 4 + wave;
    if (i >= N) return;
    int s0 = rowstart[i], s1 = rowstart[i + 1];
    float ax = 0.f, ay = 0.f;
    int n = s0;
    for (; n + 7 < s1; n += 8) {
        int s[8];
        float w[8];
        float2 r[8];
#pragma unroll
        for (int q = 0; q < 8; ++q) s[q] = adj[n + q];
#pragma unroll
        for (int q = 0; q < 8; ++q) w[q] = dinv[s[q]];
#pragma unroll
        for (int q = 0; q < 8; ++q)
            r[q] = __half22float2(((const __half2*)(h1 + (size_t)s[q] * FDIM))[lane]);
#pragma unroll
        for (int q = 0; q < 8; ++q) {
            ax += r[q].x * w[q];
            ay += r[q].y * w[q];
        }
    }
    for (; n < s1; ++n) {
        int sa = adj[n];
        float wa = dinv[sa];
        float2 ra = __half22float2(((const __half2*)(h1 + (size_t)sa * FDIM))[lane]);
        ax += ra.x * wa;
        ay += ra.y * wa;
    }
    float di = dinv[i];
    float self = di * di;
    float2 hi = __half22float2(((const __half2*)(h1 + (size_t)i * FDIM))[lane]);
    ax = ax * di + hi.x * self;
    ay = ay * di + hi.y * self;
    float2 bb = ((const float2*)b1)[lane];
    float2 xi = ((const float2*)(x + (size_t)i * FDIM))[lane];
    float rx = fmaxf(ax + bb.x, 0.f) + xi.x;
    float ry = fmaxf(ay + bb.y, 0.f) + xi.y;
    ((__half2*)(z + (size_t)i * FDIM))[lane] = __floats2half2_rn(rx, ry);
}

// ---- tiled GEMM2: h2 = z @ W2 (fp16 in, fp16 out, dense stride 40) ----
__launch_bounds__(256, 2)
__global__ void gemm2_tiled(const __half* __restrict__ z, const float* __restrict__ W2,
                            __half* __restrict__ h2, int N) {
    __shared__ float Ws[GK][64];
    __shared__ float zs[GK][132];
    int t = threadIdx.x;
    int tx = t & 15, ty = t >> 4;
    int i0 = blockIdx.x * 128;

    float acc[8][4];
#pragma unroll
    for (int a = 0; a < 8; ++a)
#pragma unroll
        for (int b = 0; b < 4; ++b) acc[a][b] = 0.f;

    for (int kb = 0; kb < FDIM / GK; ++kb) {
        __syncthreads();
        for (int p = t; p < GK * 64; p += 256) {
            int k = p >> 6, j = p & 63;
            Ws[k][j] = (j < 40) ? W2[(size_t)(kb * GK + k) * 40 + j] : 0.f;
        }
        // stage z chunk (fp16 -> fp32), 8 halfs (16B) per thread
        int kq = (t & 3) * 8;
        int rb = t >> 2;                // 0..63
#pragma unroll
        for (int pass = 0; pass < 2; ++pass) {
            int r = pass * 64 + rb;
            int row = i0 + r;
            union { float4 v; __half2 hh[4]; } u;
            u.v = make_float4(0.f, 0.f, 0.f, 0.f);
            if (row < N) u.v = *(const float4*)(z + (size_t)row * FDIM + kb * GK + kq);
#pragma unroll
            for (int j = 0; j < 4; ++j) {
                float2 f = __half22float2(u.hh[j]);
                zs[kq + 2 * j][r] = f.x;
                zs[kq + 2 * j + 1][r] = f.y;
            }
        }
        __syncthreads();
#pragma unroll 4
        for (int k = 0; k < GK; ++k) {
            float4 a0 = *(const float4*)&zs[k][ty * 4];
            float4 a1 = *(const float4*)&zs[k][64 + ty * 4];
            float4 b0 = *(const float4*)&Ws[k][tx * 4];
            float av[8] = {a0.x, a0.y, a0.z, a0.w, a1.x, a1.y, a1.z, a1.w};
            float bv[4] = {b0.x, b0.y, b0.z, b0.w};
#pragma unroll
            for (int a = 0; a < 8; ++a)
#pragma unroll
                for (int b = 0; b < 4; ++b) acc[a][b] += av[a] * bv[b];
        }
    }
    if (tx < 10) {
#pragma unroll
        for (int g = 0; g < 2; ++g)
#pragma unroll
            for (int a = 0; a < 4; ++a) {
                int row = i0 + g * 64 + ty * 4 + a;
                if (row < N) {
                    int ri = g * 4 + a;
                    union { __half2 hh[2]; float2 f; } u;
                    u.hh[0] = __floats2half2_rn(acc[ri][0], acc[ri][1]);
                    u.hh[1] = __floats2half2_rn(acc[ri][2], acc[ri][3]);
                    *(float2*)(h2 + (size_t)row * 40 + tx * 4) = u.f;
                }
            }
    }
}

// y[i,:] = dinv[i]*(sum_s h2[s,:]*dinv[s] + h2[i,:]*dinv[i]) + b2
// wave per node; 3 edge-groups x 20 feat-lanes; 4 edges per group in flight.
__global__ void agg2_kernel(const __half* __restrict__ h2, const int* __restrict__ rowstart,
                            const int* __restrict__ adj, const float* __restrict__ dinv,
                            const float* __restrict__ b2, float* __restrict__ y, int N) {
    int wave = threadIdx.x >> 6;
    int lane = threadIdx.x & 63;
    int i = blockIdx.x * 4 + wave;
    if (i >= N) return;
    int e = (lane >= 40) ? 2 : ((lane >= 20) ? 1 : 0);
    int f = lane - 20 * e;
    int s0 = rowstart[i], s1 = rowstart[i + 1];
    float ax = 0.f, ay = 0.f;
    if (lane < 60) {
        int n = s0 + e;
        for (; n + 9 < s1; n += 12) {   // 4 edges per group per iter
            int s[4];
            float w[4];
            float2 r[4];
#pragma unroll
            for (int q = 0; q < 4; ++q) s[q] = adj[n + 3 * q];
#pragma unroll
            for (int q = 0; q < 4; ++q) w[q] = dinv[s[q]];
#pragma unroll
            for (int q = 0; q < 4; ++q)
                r[q] = __half22float2(((const __half2*)(h2 + (size_t)s[q] * 40))[f]);
#pragma unroll
            for (int q = 0; q < 4; ++q) {
                ax += r[q].x * w[q];
                ay += r[q].y * w[q];
            }
        }
        for (; n < s1; n += 3) {
            int sa = adj[n];
            float wa = dinv[sa];
            float2 ra = __half22float2(((const __half2*)(h2 + (size_t)sa * 40))[f]);
            ax += ra.x * wa;
            ay += ra.y * wa;
        }
    }
    float sx = ax + __shfl(ax, lane + 20, 64) + __shfl(ax, lane + 40, 64);
    float sy = ay + __shfl(ay, lane + 20, 64) + __shfl(ay, lane + 40, 64);
    if (lane < 20) {
        float di = dinv[i];
        float2 hi = __half22float2(((const __half2*)(h2 + (size_t)i * 40))[lane]);
        float2 bb = ((const float2*)b2)[lane];
        float2 res;
        res.x = sx * di + hi.x * di * di + bb.x;
        res.y = sy * di + hi.y * di * di + bb.y;
        ((float2*)(y + (size_t)i * 40))[lane] = res;
    }
}

extern "C" void kernel_launch(void* const* d_in, const int* in_sizes, int n_in,
                              void* d_out, int out_size, void* d_ws, size_t ws_size,
                              hipStream_t stream) {
    const float* x  = (const float*)d_in[0];
    const int*   ei = (const int*)d_in[1];
    const float* W1 = (const float*)d_in[2];
    const float* b1 = (const float*)d_in[3];
    const float* W2 = (const float*)d_in[4];
    const float* b2 = (const float*)d_in[5];
    float* y = (float*)d_out;

    const int H = in_sizes[3];           // 128
    const int F = in_sizes[2] / H;       // 128
    const int N = in_sizes[0] / F;       // 50000
    const int E = in_sizes[1] / 2;       // 800000
    (void)H; (void)ws_size; (void)n_in; (void)out_size;

    size_t off = 0;
    auto carve = [&](size_t bytes) -> void* {
        void* p = (char*)d_ws + off;
        off += (bytes + 255) & ~(size_t)255;
        return p;
    };
    // deg & cursor adjacent -> single memset covers both (plus pad)
    char*   zero0    = (char*)d_ws;
    int*    deg      = (int*)carve((size_t)N * 4);
    int*    cursor   = (int*)carve((size_t)N * 4);
    size_t  zlen     = off;
    int*    rowstart = (int*)carve((size_t)(N + 1) * 4);
    float*  dinv     = (float*)carve((size_t)N * 4);
    int*    blocksum = (int*)carve(256 * 4);
    int*    adj      = (int*)carve((size_t)E * 4);
    __half* h1       = (__half*)carve((size_t)N * FDIM * 2);
    __half* z        = (__half*)carve((size_t)N * FDIM * 2);
    __half* h2       = h1;   // h1 dead after agg1; h2 = N x 40 fp16 (fits)

    hipMemsetAsync(zero0, 0, zlen, stream);

    int e4b = (E / 4 + 256) / 256;       // covers E/4 threads (+tail thread)
    int nbs = (N + 255) / 256;           // <=256 required by scan_bc
    count_deg_kernel<<<e4b, 256, 0, stream>>>(ei, E, deg);
    scan_a_kernel<<<nbs, 256, 0, stream>>>(deg, N, rowstart, blocksum, dinv);
    scan_bc_kernel<<<nbs, 256, 0, stream>>>(N, blocksum, nbs, rowstart);
    fill_adj_kernel<<<e4b, 256, 0, stream>>>(ei, E, rowstart, cursor, adj);

    int nbt = (N + 127) / 128;
    gemm1_tiled<<<nbt, 256, 0, stream>>>(x, W1, h1, N);
    agg1_kernel<<<(N + 3) / 4, 256, 0, stream>>>(h1, rowstart, adj, dinv, x, b1, z, N);
    gemm2_tiled<<<nbt, 256, 0, stream>>>(z, W2, h2, N);
    agg2_kernel<<<(N + 3) / 4, 256, 0, stream>>>(h2, rowstart, adj, dinv, b2, y, N);
}